// Round 3
// baseline (1871.461 us; speedup 1.0000x reference)
//
#include <hip/hip_runtime.h>

typedef unsigned short ushort_t;
typedef __attribute__((ext_vector_type(4))) float f32x4;
typedef __attribute__((ext_vector_type(8))) short bf16x8;
typedef __attribute__((ext_vector_type(4))) unsigned short u16x4;

#define MFMA(a, b, c) __builtin_amdgcn_mfma_f32_16x16x32_bf16((a), (b), (c), 0, 0, 0)

__device__ __forceinline__ unsigned short f2bf(float f) {
    unsigned int u = __builtin_bit_cast(unsigned int, f);
    u += 0x7fffu + ((u >> 16) & 1u);   // round-to-nearest-even
    return (unsigned short)(u >> 16);
}
__device__ __forceinline__ float bf2f(unsigned short h) {
    unsigned int u = ((unsigned int)h) << 16;
    return __builtin_bit_cast(float, u);
}
__device__ __forceinline__ void split2(float f, unsigned short& h, unsigned short& l) {
    h = f2bf(f);
    l = f2bf(f - bf2f(h));
}

// Stage a (512 c x 64 n) f32 c-major matrix into LDS as (64 rows x 512 cols)
// bf16 hi/lo, rows 1024B, XOR-swizzled (row&7)<<4 so ds_read_b128 A-fragments
// are conflict-free. Each quad: 1 row x 4 cols -> packed ds_write_b64.
__device__ __forceinline__ void stage_split(const float* __restrict__ src,
                                            char* sh, char* sl, int tid) {
    #pragma unroll
    for (int i = 0; i < 16; ++i) {
        int u = tid + i * 512;           // 8192 quads, 512 threads
        int n = u & 63;                  // row (token); wave = 64 consecutive n -> coalesced
        int c0 = (u >> 6) << 2;          // column base (k), 0..508
        u16x4 hv, lv;
        #pragma unroll
        for (int j = 0; j < 4; ++j) {
            float f = src[(size_t)(c0 + j) * 64 + n];
            unsigned short hh, ll;
            split2(f, hh, ll);
            hv[j] = hh;
            lv[j] = ll;
        }
        int off = n * 1024 + ((2 * c0) ^ ((n & 7) << 4));
        *(u16x4*)(sh + off) = hv;
        *(u16x4*)(sl + off) = lv;
    }
}

// ---- Prep: transpose W (K x N) -> T (N x K) and split into bf16 hi/lo ----
__global__ __launch_bounds__(256) void wsplit_kernel(const float* __restrict__ W,
                                                     ushort_t* __restrict__ Thi,
                                                     ushort_t* __restrict__ Tlo,
                                                     int K, int N) {
    __shared__ float tile[64][65];
    int nb = N >> 6;
    int bx = blockIdx.x % nb;
    int by = blockIdx.x / nb;
    int n0 = bx * 64, k0 = by * 64;
    int t = threadIdx.x;
    int c4 = (t & 15) * 4;
    int rr = t >> 4;
    #pragma unroll
    for (int i = 0; i < 4; ++i) {
        int r = rr + i * 16;
        f32x4 vv = *(const f32x4*)(W + (size_t)(k0 + r) * N + n0 + c4);
        tile[r][c4 + 0] = vv[0];
        tile[r][c4 + 1] = vv[1];
        tile[r][c4 + 2] = vv[2];
        tile[r][c4 + 3] = vv[3];
    }
    __syncthreads();
    #pragma unroll
    for (int i = 0; i < 4; ++i) {
        int rn = rr + i * 16;            // local n (output row)
        u16x4 hv, lv;
        #pragma unroll
        for (int r2 = 0; r2 < 4; ++r2) {
            unsigned short hh, ll;
            split2(tile[c4 + r2][rn], hh, ll);
            hv[r2] = hh;
            lv[r2] = ll;
        }
        *(u16x4*)(Thi + (size_t)(n0 + rn) * K + k0 + c4) = hv;
        *(u16x4*)(Tlo + (size_t)(n0 + rn) * K + k0 + c4) = lv;
    }
}

// ---- Prep: gather relative-position bias into dense (H, 64, 64) f32 ----
__global__ __launch_bounds__(256) void biasM_kernel(const float* __restrict__ table,
                                                    float* __restrict__ biasM) {
    int u = blockIdx.x * 256 + threadIdx.x;   // 65536 = 16*64*64
    int h = u >> 12;
    int n = (u >> 6) & 63;
    int m = u & 63;
    int idx = ((n >> 3) - (m >> 3) + 7) * 15 + ((n & 7) - (m & 7) + 7);
    biasM[u] = table[idx * 16 + h];
}

// ---- Fused kernel: QKV proj + dual-activation attention + output proj ----
// grid 1024 (one block per window), 512 threads (8 waves), 159744 B dyn LDS.
// Per-head rank-32 proj update accumulates out = ao @ Wp in registers; no
// intermediate ever touches HBM. Proj B-fragments register-reused across all
// 4 n-tiles (each Wp element fetched once per block).
__global__ __launch_bounds__(512, 2) void attn_kernel(
    const float* __restrict__ x,
    const ushort_t* __restrict__ WqTh, const ushort_t* __restrict__ WqTl,
    const ushort_t* __restrict__ WkvTh, const ushort_t* __restrict__ WkvTl,
    const float* __restrict__ bq, const float* __restrict__ bkv,
    const float* __restrict__ biasM, const float* __restrict__ wbl,
    const ushort_t* __restrict__ WpTh, const ushort_t* __restrict__ WpTl,
    const float* __restrict__ bp, float* __restrict__ out) {
    extern __shared__ char sm[];
    char* xs_h = sm;                 // 64KB  x hi (64 x 512 bf16, swizzled)
    char* xs_l = sm + 65536;         // 64KB  x lo
    char* q_h = sm + 131072;         // 5KB   q hi (64 rows x 80B)
    char* q_l = sm + 136192;         // 5KB
    char* k_h = sm + 141312;         // 5KB
    char* k_l = sm + 146432;         // 5KB
    char* v_h = sm + 151552;         // 4KB   vT hi (32 rows x 128B, swizzled)
    char* v_l = sm + 155648;         // 4KB   -> total 159744
    char* a_h = q_h;                 // attn weights alias q (8KB, barrier-separated)
    char* a_l = k_h;                 // alias k
    char* ao_h = q_h;                // per-head attn output, alias (post-PV)
    char* ao_l = k_h;

    const int b = blockIdx.x;
    const int tid = threadIdx.x;

    stage_split(x + (size_t)b * 32768, xs_h, xs_l, tid);

    const int l = tid & 63;
    const int w = tid >> 6;
    const int ln = l & 15;
    const int g = l >> 4;
    const int nt = w >> 1;           // row-tile 0..3
    const int dt = w & 1;            // d-tile 0..1
    const int nA = nt * 16 + ln;     // A-fragment row
    const int nC = nt * 16 + g * 4;  // C row base
    const int dcol = dt * 16 + ln;   // output column within 32 (d)
    const int swA = (nA & 7) << 4;

    float wb0 = wbl[0], wb1 = wbl[1];
    float wm = fmaxf(wb0, wb1);
    float e0 = __expf(wb0 - wm), e1 = __expf(wb1 - wm);
    float wt0 = e0 / (e0 + e1), wt1 = e1 / (e0 + e1);

    // out accumulators: acc[ctl*4+ntl][r] = out[ntl*16 + g*4 + r][w*64 + ctl*16 + ln]
    f32x4 acc[16];
    #pragma unroll
    for (int i = 0; i < 16; ++i) acc[i] = {0.f, 0.f, 0.f, 0.f};

    __syncthreads();

    for (int h = 0; h < 16; ++h) {
        // ---------- Q-phase: q,k,v = xf @ W (+bias), bf16 hi/lo split ----------
        const int cq = h * 32 + dcol;
        float bqv = bq[cq];
        float bkvv = bkv[cq];
        float bvv = bkv[512 + cq];
        const ushort_t* pqh = WqTh + (size_t)cq * 512 + g * 8;
        const ushort_t* pql = WqTl + (size_t)cq * 512 + g * 8;
        const ushort_t* pkh = WkvTh + (size_t)cq * 512 + g * 8;
        const ushort_t* pkl = WkvTl + (size_t)cq * 512 + g * 8;
        const ushort_t* pvh = WkvTh + (size_t)(512 + cq) * 512 + g * 8;
        const ushort_t* pvl = WkvTl + (size_t)(512 + cq) * 512 + g * 8;

        f32x4 aq0 = {0.f, 0.f, 0.f, 0.f}, aq1 = {0.f, 0.f, 0.f, 0.f};
        f32x4 ak0 = {0.f, 0.f, 0.f, 0.f}, ak1 = {0.f, 0.f, 0.f, 0.f};
        f32x4 av0 = {0.f, 0.f, 0.f, 0.f}, av1 = {0.f, 0.f, 0.f, 0.f};
        #pragma unroll
        for (int kk = 0; kk < 8; ++kk) {
            const int k0 = kk * 64;
            {
                int off = nA * 1024 + ((2 * (k0 + g * 8)) ^ swA);
                bf16x8 Ah = *(const bf16x8*)(xs_h + off);
                bf16x8 Al = *(const bf16x8*)(xs_l + off);
                bf16x8 Bh = *(const bf16x8*)(pqh + k0);
                bf16x8 Bl = *(const bf16x8*)(pql + k0);
                aq0 = MFMA(Ah, Bh, aq0);
                aq0 = MFMA(Ah, Bl, aq0);
                aq0 = MFMA(Al, Bh, aq0);
                Bh = *(const bf16x8*)(pkh + k0);
                Bl = *(const bf16x8*)(pkl + k0);
                ak0 = MFMA(Ah, Bh, ak0);
                ak0 = MFMA(Ah, Bl, ak0);
                ak0 = MFMA(Al, Bh, ak0);
                Bh = *(const bf16x8*)(pvh + k0);
                Bl = *(const bf16x8*)(pvl + k0);
                av0 = MFMA(Ah, Bh, av0);
                av0 = MFMA(Ah, Bl, av0);
                av0 = MFMA(Al, Bh, av0);
            }
            {
                const int k1 = k0 + 32;
                int off = nA * 1024 + ((2 * (k1 + g * 8)) ^ swA);
                bf16x8 Ah = *(const bf16x8*)(xs_h + off);
                bf16x8 Al = *(const bf16x8*)(xs_l + off);
                bf16x8 Bh = *(const bf16x8*)(pqh + k1);
                bf16x8 Bl = *(const bf16x8*)(pql + k1);
                aq1 = MFMA(Ah, Bh, aq1);
                aq1 = MFMA(Ah, Bl, aq1);
                aq1 = MFMA(Al, Bh, aq1);
                Bh = *(const bf16x8*)(pkh + k1);
                Bl = *(const bf16x8*)(pkl + k1);
                ak1 = MFMA(Ah, Bh, ak1);
                ak1 = MFMA(Ah, Bl, ak1);
                ak1 = MFMA(Al, Bh, ak1);
                Bh = *(const bf16x8*)(pvh + k1);
                Bl = *(const bf16x8*)(pvl + k1);
                av1 = MFMA(Ah, Bh, av1);
                av1 = MFMA(Ah, Bl, av1);
                av1 = MFMA(Al, Bh, av1);
            }
        }
        f32x4 aq = aq0 + aq1;
        f32x4 ak2 = ak0 + ak1;
        f32x4 av = av0 + av1;

        // store q (pre-scaled), k as (token, d) rows of 80B
        #pragma unroll
        for (int r = 0; r < 4; ++r) {
            int nr = nC + r;
            unsigned short hh, ll;
            split2((aq[r] + bqv) * 0.17677669529663689f, hh, ll);
            *(unsigned short*)(q_h + nr * 80 + 2 * dcol) = hh;
            *(unsigned short*)(q_l + nr * 80 + 2 * dcol) = ll;
            split2(ak2[r] + bkvv, hh, ll);
            *(unsigned short*)(k_h + nr * 80 + 2 * dcol) = hh;
            *(unsigned short*)(k_l + nr * 80 + 2 * dcol) = ll;
        }
        // store v transposed (d, token), swizzled, packed 4x bf16
        {
            u16x4 vh4, vl4;
            #pragma unroll
            for (int r = 0; r < 4; ++r) {
                unsigned short hh, ll;
                split2(av[r] + bvv, hh, ll);
                vh4[r] = hh;
                vl4[r] = ll;
            }
            int voff = dcol * 128 + ((2 * nC) ^ ((dcol & 7) << 4));
            *(u16x4*)(v_h + voff) = vh4;
            *(u16x4*)(v_l + voff) = vl4;
        }
        __syncthreads();

        // ---------- S-phase: s = q k^T + bias; dual softmax/relu^2 blend ----------
        f32x4 sv[4];
        float ex[4][4];
        float rinv0[4];
        if (w < 4) {
            int offq = (w * 16 + ln) * 80 + 16 * g;
            bf16x8 Qh = *(const bf16x8*)(q_h + offq);
            bf16x8 Ql = *(const bf16x8*)(q_l + offq);
            #pragma unroll
            for (int mt = 0; mt < 4; ++mt) {
                int offk = (mt * 16 + ln) * 80 + 16 * g;
                bf16x8 Kh = *(const bf16x8*)(k_h + offk);
                bf16x8 Kl = *(const bf16x8*)(k_l + offk);
                f32x4 s = {0.f, 0.f, 0.f, 0.f};
                s = MFMA(Qh, Kh, s);
                s = MFMA(Qh, Kl, s);
                s = MFMA(Ql, Kh, s);
                sv[mt] = s;
            }
            const float* bM = biasM + h * 4096;
            #pragma unroll
            for (int r = 0; r < 4; ++r) {
                int n_ = w * 16 + g * 4 + r;
                #pragma unroll
                for (int mt = 0; mt < 4; ++mt)
                    sv[mt][r] += bM[n_ * 64 + mt * 16 + ln];
            }
            #pragma unroll
            for (int r = 0; r < 4; ++r) {
                float mx = fmaxf(fmaxf(sv[0][r], sv[1][r]), fmaxf(sv[2][r], sv[3][r]));
                mx = fmaxf(mx, __shfl_xor(mx, 1));
                mx = fmaxf(mx, __shfl_xor(mx, 2));
                mx = fmaxf(mx, __shfl_xor(mx, 4));
                mx = fmaxf(mx, __shfl_xor(mx, 8));
                float sum = 0.f;
                #pragma unroll
                for (int mt = 0; mt < 4; ++mt) {
                    float e = __expf(sv[mt][r] - mx);
                    ex[mt][r] = e;
                    sum += e;
                }
                sum += __shfl_xor(sum, 1);
                sum += __shfl_xor(sum, 2);
                sum += __shfl_xor(sum, 4);
                sum += __shfl_xor(sum, 8);
                rinv0[r] = wt0 / sum;
            }
        }
        __syncthreads();   // all QK^T reads of q/k done before aliasing with a
        if (w < 4) {
            #pragma unroll
            for (int mt = 0; mt < 4; ++mt) {
                int m_ = mt * 16 + ln;
                #pragma unroll
                for (int r = 0; r < 4; ++r) {
                    int n_ = w * 16 + g * 4 + r;
                    float rl = fmaxf(sv[mt][r], 0.f);
                    float aval = ex[mt][r] * rinv0[r] + wt1 * rl * rl;
                    unsigned short hh, ll;
                    split2(aval, hh, ll);
                    int aoff = n_ * 128 + ((2 * m_) ^ ((n_ & 7) << 4));
                    *(unsigned short*)(a_h + aoff) = hh;
                    *(unsigned short*)(a_l + aoff) = ll;
                }
            }
        }
        __syncthreads();

        // ---------- PV: ao = a @ v ----------
        f32x4 ao = {0.f, 0.f, 0.f, 0.f};
        {
            const int swV = (dcol & 7) << 4;
            #pragma unroll
            for (int ks = 0; ks < 2; ++ks) {
                int mo = 2 * (ks * 32 + g * 8);
                bf16x8 Aa = *(const bf16x8*)(a_h + nA * 128 + (mo ^ swA));
                bf16x8 Ab = *(const bf16x8*)(a_l + nA * 128 + (mo ^ swA));
                bf16x8 Vh = *(const bf16x8*)(v_h + dcol * 128 + (mo ^ swV));
                bf16x8 Vl = *(const bf16x8*)(v_l + dcol * 128 + (mo ^ swV));
                ao = MFMA(Aa, Vh, ao);
                ao = MFMA(Aa, Vl, ao);
                ao = MFMA(Ab, Vh, ao);
            }
        }
        __syncthreads();   // a reads done before ao overwrites the region

        // ---------- ao -> LDS (hi/lo, 80B rows, same pattern as q/k) ----------
        #pragma unroll
        for (int r = 0; r < 4; ++r) {
            unsigned short hh, ll;
            split2(ao[r], hh, ll);
            *(unsigned short*)(ao_h + (nC + r) * 80 + 2 * dcol) = hh;
            *(unsigned short*)(ao_l + (nC + r) * 80 + 2 * dcol) = ll;
        }
        __syncthreads();

        // ---------- proj accumulate: out += ao_head @ Wp[head k-slice] ----------
        // Wave w owns out col-tiles [w*64, w*64+64); B-fragment loaded once and
        // reused across all 4 n-tiles (Wp fetched exactly once per block).
        {
            bf16x8 Ah[4], Al[4];
            #pragma unroll
            for (int ntl = 0; ntl < 4; ++ntl) {
                int offa = (ntl * 16 + ln) * 80 + 16 * g;
                Ah[ntl] = *(const bf16x8*)(ao_h + offa);
                Al[ntl] = *(const bf16x8*)(ao_l + offa);
            }
            const ushort_t* ph = WpTh + (size_t)(w * 64 + ln) * 512 + h * 32 + g * 8;
            const ushort_t* pl = WpTl + (size_t)(w * 64 + ln) * 512 + h * 32 + g * 8;
            #pragma unroll
            for (int ctl = 0; ctl < 4; ++ctl) {
                bf16x8 Bh = *(const bf16x8*)(ph + (size_t)ctl * 8192);
                bf16x8 Bl = *(const bf16x8*)(pl + (size_t)ctl * 8192);
                #pragma unroll
                for (int ntl = 0; ntl < 4; ++ntl) {
                    acc[ctl * 4 + ntl] = MFMA(Ah[ntl], Bh, acc[ctl * 4 + ntl]);
                    acc[ctl * 4 + ntl] = MFMA(Ah[ntl], Bl, acc[ctl * 4 + ntl]);
                    acc[ctl * 4 + ntl] = MFMA(Al[ntl], Bh, acc[ctl * 4 + ntl]);
                }
            }
        }
        __syncthreads();   // proj reads done before next head's q/k/v stores
    }

    // ---------- epilogue: add bias, store out (B, C, N) ----------
    #pragma unroll
    for (int ctl = 0; ctl < 4; ++ctl) {
        int cout = w * 64 + ctl * 16 + ln;
        float bb = bp[cout];
        #pragma unroll
        for (int ntl = 0; ntl < 4; ++ntl) {
            f32x4 o;
            #pragma unroll
            for (int r = 0; r < 4; ++r) o[r] = acc[ctl * 4 + ntl][r] + bb;
            *(f32x4*)(out + ((size_t)b * 512 + cout) * 64 + ntl * 16 + g * 4) = o;
        }
    }
}

extern "C" void kernel_launch(void* const* d_in, const int* in_sizes, int n_in,
                              void* d_out, int out_size, void* d_ws, size_t ws_size,
                              hipStream_t stream) {
    const float* x = (const float*)d_in[0];
    const float* Wq = (const float*)d_in[1];
    const float* bq = (const float*)d_in[2];
    const float* Wkv = (const float*)d_in[3];
    const float* bkv = (const float*)d_in[4];
    const float* btab = (const float*)d_in[5];
    const float* wbl = (const float*)d_in[6];
    const float* Wp = (const float*)d_in[7];
    const float* bp = (const float*)d_in[8];
    float* out = (float*)d_out;

    char* ws = (char*)d_ws;
    // ws layout (bytes) — total ~4.5MB
    ushort_t* WqTh = (ushort_t*)(ws + 0);          //  512x512 bf16 = 512KB
    ushort_t* WqTl = (ushort_t*)(ws + 524288);
    ushort_t* WkvTh = (ushort_t*)(ws + 1048576);   // 1024x512 bf16 = 1MB
    ushort_t* WkvTl = (ushort_t*)(ws + 2097152);
    ushort_t* WpTh = (ushort_t*)(ws + 3145728);
    ushort_t* WpTl = (ushort_t*)(ws + 3670016);
    float* biasM = (float*)(ws + 4194304);         // 16x64x64 f32 = 256KB

    wsplit_kernel<<<64, 256, 0, stream>>>(Wq, WqTh, WqTl, 512, 512);
    wsplit_kernel<<<128, 256, 0, stream>>>(Wkv, WkvTh, WkvTl, 512, 1024);
    wsplit_kernel<<<64, 256, 0, stream>>>(Wp, WpTh, WpTl, 512, 512);
    biasM_kernel<<<256, 256, 0, stream>>>(btab, biasM);

    (void)hipFuncSetAttribute((const void*)attn_kernel,
                              hipFuncAttributeMaxDynamicSharedMemorySize, 159744);

    attn_kernel<<<1024, 512, 159744, stream>>>(x, WqTh, WqTl, WkvTh, WkvTl,
                                               bq, bkv, biasM, wbl,
                                               WpTh, WpTl, bp, out);
}